// Round 10
// baseline (869.456 us; speedup 1.0000x reference)
//
#include <hip/hip_runtime.h>
#include <hip/hip_bf16.h>
#include <math.h>
#include <cstdint>

typedef unsigned long long u64;
typedef unsigned int u32;
typedef _Float16 half8 __attribute__((ext_vector_type(8)));
typedef float floatx4 __attribute__((ext_vector_type(4)));

// ---------------------------------------------------------------------------
#define NANCH 36864
#define N_PRE 6000
#define N_POST 300
#define NW 96
#define NPADC 6144

// output float offsets
#define O0 0
#define O1 294912
#define O2 442368
#define O3 444768
#define O4 445368
#define O5 592824

// workspace float offsets
#define WS_XHI   0
#define WS_XLO   2097152
#define WS_WHI   4194304
#define WS_WLO   5373952
#define WS_WSLT  6553600
#define WS_WSLB  6586368
#define WS_H     6586432
#define WS_GUARD 10780736
// overlays into dead XHI region (after conv):
#define WS_FG    0
#define WS_ROI   73728
#define WS_KEYS  368640
#define WS_SBOX  630784
#define WS_ALIVE 679936
#define WS_CKEYS 680320
#define WS_CNT   717184                  // cnt[2], bar at +2
#define WS_CUT   717248
#define WS_PART  717312                  // 512 u32
// overlay into dead XLO region: 2^18-bin histogram
#define WS_HIST2 2097152
// overlay into dead WHI+WLO region: suppression matrix
#define WS_MASK  4194304

#define HSCALE 9.5367431640625e-07f      // 2^-20

// ---------------------------------------------------------------------------
__device__ __forceinline__ void gl_lds16(const void* g, void* l) {
  __builtin_amdgcn_global_load_lds(
      (const __attribute__((address_space(1))) u32*)g,
      (__attribute__((address_space(3))) u32*)l, 16, 0, 0);
}

__device__ __forceinline__ u64 bcast64(u64 v, int src) {
  u32 lo = (u32)__shfl((int)(v & 0xFFFFFFFFull), src);
  u32 hi = (u32)__shfl((int)(v >> 32), src);
  return ((u64)hi << 32) | lo;
}

// Manual grid barrier. Safe: tail grid (288 blocks, 64KB LDS) is co-resident
// by construction (2 blocks/CU x 256 CU = 512 slots >= 288). Verified live
// in R9 (kernel completed; failure was an unrelated indexing bug).
__device__ __forceinline__ void gridbar(u32* bar, u32 target) {
  __syncthreads();
  if (threadIdx.x == 0) {
    __threadfence();
    atomicAdd(bar, 1u);
    while (atomicAdd(bar, 0u) < target) __builtin_amdgcn_s_sleep(8);
  }
  __syncthreads();
  __threadfence();
}

// ---------------------------------------------------------------------------
// 0. fused prep: zero hbuf+guard | xcvt | wcvt | head-weight pack.
// ---------------------------------------------------------------------------
__global__ __launch_bounds__(256) void prep_all(
    const float* __restrict__ x, const float* __restrict__ w,
    const float* __restrict__ lw, const float* __restrict__ sw,
    const float* __restrict__ lb, const float* __restrict__ sb,
    float4* __restrict__ h, float4* __restrict__ guard,
    _Float16* __restrict__ xhi, _Float16* __restrict__ xlo,
    _Float16* __restrict__ whi, _Float16* __restrict__ wlo,
    float* __restrict__ wslt, float* __restrict__ wslb) {
  __shared__ float s[64 * 65];
  const int b = blockIdx.x, tid = threadIdx.x;
  if (b < 4097) {
    int idx = b * 256 + tid;
    if (idx < 1048576) h[idx] = make_float4(0.f, 0.f, 0.f, 0.f);
    else if (idx < 1048576 + 16) guard[idx - 1048576] = make_float4(0.f, 0.f, 0.f, 0.f);
    return;
  }
  if (b < 5121) {  // xcvt
    int l = b - 4097;
    int pt = l & 63, cg = (l >> 6) & 7, n = l >> 9;
    const int c0 = cg << 6, p0 = pt << 6;
#pragma unroll
    for (int kk = 0; kk < 16; ++kk) {
      int e = tid + (kk << 8);
      int ci = e >> 6, pi = e & 63;
      s[ci * 65 + pi] = x[(((size_t)(n * 512 + c0 + ci)) << 12) + p0 + pi];
    }
    __syncthreads();
#pragma unroll
    for (int kk = 0; kk < 16; ++kk) {
      int e = tid + (kk << 8);
      int ci = e & 63, pi = e >> 6;
      float sv = s[ci * 65 + pi] * 1024.f;
      _Float16 hi = (_Float16)sv;
      _Float16 lo = (_Float16)(sv - (float)hi);
      size_t off = (((size_t)(n << 12) + p0 + pi) << 9) + c0 + ci;
      xhi[off] = hi;
      xlo[off] = lo;
    }
    return;
  }
  if (b < 5697) {  // wcvt
    int l = b - 5121;
    int ct = l & 7, ot = (l >> 3) & 7, t = l >> 6;
    const int c0 = ct << 6, o0 = ot << 6;
#pragma unroll
    for (int kk = 0; kk < 16; ++kk) {
      int e = tid + (kk << 8);
      int ci = e & 63, oi = e >> 6;
      float sv = w[(size_t)(o0 + oi) * 4608 + (c0 + ci) * 9 + t] * 1024.f;
      _Float16 hi = (_Float16)sv;
      _Float16 lo = (_Float16)(sv - (float)hi);
      size_t off = ((size_t)((t << 9) + o0 + oi) << 9) + c0 + ci;
      whi[off] = hi;
      wlo[off] = lo;
    }
    return;
  }
  {  // prep_small
    int e = (b - 5697) * 256 + tid;
    if (e < 32768) {
      int c = e >> 6, o = e & 63;
      float v = 0.f;
      if (o < 36) v = lw[o * 512 + c];
      else if (o < 54) v = sw[(o - 36) * 512 + c];
      wslt[e] = v;
    } else if (e < 32832) {
      int o = e - 32768;
      float v = 0.f;
      if (o < 36) v = lb[o];
      else if (o < 54) v = sb[o - 36];
      wslb[o] = v;
    }
  }
}

// ---------------------------------------------------------------------------
// 1. MFMA implicit-GEMM 3x3 conv. fp16x2 split, swizzled LDS (0 conflicts),
// K-split x2 (grid.z == 2 exactly).
// ---------------------------------------------------------------------------
__global__ __launch_bounds__(256) void conv_mfma(
    const _Float16* __restrict__ xhi, const _Float16* __restrict__ xlo,
    const _Float16* __restrict__ whi, const _Float16* __restrict__ wlo,
    const float* __restrict__ guard, float* __restrict__ hout) {
  __shared__ _Float16 aHi[4 * 68 * 32];
  __shared__ _Float16 aLo[4 * 68 * 32];
  __shared__ _Float16 bHi[128 * 32];
  __shared__ _Float16 bLo[128 * 32];
  const int tid = threadIdx.x;
  const int lane = tid & 63, w = tid >> 6;
  const int ptile = blockIdx.x;
  const int og = blockIdx.y;
  const int kq = blockIdx.z;           // 0..1
  const int y0 = (ptile & 31) << 1;
  const int nimg = ptile >> 5;
  const int o0 = og << 7;
  const int l15 = lane & 15, l16 = lane >> 4;
  const int ry = w >> 1;
  const int wo = (w & 1) << 6;

  floatx4 acc[4][4];
#pragma unroll
  for (int a = 0; a < 4; ++a)
#pragma unroll
    for (int b = 0; b < 4; ++b) acc[a][b] = (floatx4)0.f;

  for (int s = 0; s < 8; ++s) {
    const int c0 = (kq << 8) + (s << 5);
    __syncthreads();
    for (int i = w; i < 17; i += 4) {
      int chunk = (i << 6) + lane;
      int p = chunk >> 2;
      int q = ((chunk & 3) - ((chunk >> 3) & 3)) & 3;   // swizzled k-slot
      int r = p / 68, xs = p - r * 68;
      int y = y0 - 1 + r, xg = xs - 1;
      bool ok = ((unsigned)y < 64u) && ((unsigned)xg < 64u);
      size_t off = (((size_t)(nimg << 12) + (y << 6) + xg) << 9) + c0 + (q << 3);
      const void* gh = ok ? (const void*)(xhi + off) : (const void*)guard;
      const void* gl = ok ? (const void*)(xlo + off) : (const void*)guard;
      gl_lds16(gh, (char*)aHi + (i << 10));
      gl_lds16(gl, (char*)aLo + (i << 10));
    }
    for (int tt = 0; tt < 9; ++tt) {
      if (tt > 0) __syncthreads();
      for (int i = w; i < 8; i += 4) {
        int chunk = (i << 6) + lane;
        int row = chunk >> 2;
        int q = ((chunk & 3) - ((chunk >> 3) & 3)) & 3;
        size_t off = ((size_t)((tt << 9) + o0 + row) << 9) + c0 + (q << 3);
        gl_lds16((const void*)(whi + off), (char*)bHi + (i << 10));
        gl_lds16((const void*)(wlo + off), (char*)bLo + (i << 10));
      }
      __syncthreads();

      const int dy = tt / 3, dx = tt - 3 * dy;
      half8 ah[4], al[4], bh[4], bl[4];
#pragma unroll
      for (int im = 0; im < 4; ++im) {
        int xp = (im << 4) + l15;
        int P = (ry + dy) * 68 + xp + dx;
        int sw = ((l16 + (P >> 1)) & 3) << 3;
        ah[im] = *(const half8*)&aHi[(P << 5) + sw];
        al[im] = *(const half8*)&aLo[(P << 5) + sw];
      }
#pragma unroll
      for (int in = 0; in < 4; ++in) {
        int orow = wo + (in << 4) + l15;
        int swb = ((l16 + (orow >> 1)) & 3) << 3;
        bh[in] = *(const half8*)&bHi[(orow << 5) + swb];
        bl[in] = *(const half8*)&bLo[(orow << 5) + swb];
      }
#pragma unroll
      for (int im = 0; im < 4; ++im)
#pragma unroll
        for (int in = 0; in < 4; ++in) {
          acc[im][in] = __builtin_amdgcn_mfma_f32_16x16x32_f16(
              ah[im], bh[in], acc[im][in], 0, 0, 0);
          acc[im][in] = __builtin_amdgcn_mfma_f32_16x16x32_f16(
              ah[im], bl[in], acc[im][in], 0, 0, 0);
          acc[im][in] = __builtin_amdgcn_mfma_f32_16x16x32_f16(
              al[im], bh[in], acc[im][in], 0, 0, 0);
        }
    }
  }

#pragma unroll
  for (int im = 0; im < 4; ++im)
#pragma unroll
    for (int in = 0; in < 4; ++in) {
      int o = o0 + wo + (in << 4) + l15;
#pragma unroll
      for (int reg = 0; reg < 4; ++reg) {
        int m_local = (ry << 6) + (im << 4) + (l16 << 2) + reg;
        size_t off = (((size_t)(nimg << 12) + (y0 << 6) + m_local) << 9) + o;
        atomicAdd(&hout[off], acc[im][in][reg]);
      }
    }
}

// ---------------------------------------------------------------------------
// 2. 1x1 heads + softmax. 32-pixel blocks -> grid (128,2) = 256 blocks.
// R9 BUG (fixed): fg pointer was fgbuf + n*NANCH + p0*9, but p0*9 already
// contains n*NANCH (NANCH = 4096*9) -> image 1's fg landed out of region.
// Correct: fg = fgbuf + p0*9.
// ---------------------------------------------------------------------------
__global__ __launch_bounds__(256) void head_kernel(
    const float* __restrict__ hbuf, const float* __restrict__ cb,
    const float* __restrict__ wslt, const float* __restrict__ wslb,
    float* __restrict__ out, float* __restrict__ fgbuf,
    float4* __restrict__ zkeys, float4* __restrict__ zhist,
    float4* __restrict__ zcnt) {
  const int y2 = blockIdx.x, n = blockIdx.y;   // y2: 0..127 (32-px tile)
  __shared__ float sH[16 * 33];
  __shared__ float sWt[1024];
  __shared__ float sOut[64 * 33];
  const int tid = threadIdx.x;
  const int x = tid & 31, og = tid >> 5;       // og 0..7 -> 8 outputs each
  const int bb = (n << 7) + y2;                // 0..255

  {  // init overlays: ckeys 8192 f4 (~0), ghist 131072 f4 (0), cnt+bar (0)
    float f = __uint_as_float(0xFFFFFFFFu);
    if (tid < 32) zkeys[(bb << 5) + tid] = make_float4(f, f, f, f);
    zhist[(bb << 9) + tid] = make_float4(0.f, 0.f, 0.f, 0.f);
    zhist[(bb << 9) + 256 + tid] = make_float4(0.f, 0.f, 0.f, 0.f);
    if (bb == 0 && tid < 16) zcnt[tid] = make_float4(0.f, 0.f, 0.f, 0.f);
  }

  float acc[8];
#pragma unroll
  for (int j = 0; j < 8; ++j) acc[j] = 0.f;

  const float* hb = hbuf + (((size_t)(n << 12) + (y2 << 5)) << 9);

  for (int c0 = 0; c0 < 512; c0 += 16) {
    __syncthreads();
    if (tid < 128) {
      int xx = tid >> 2, cc4 = (tid & 3) << 2;
      float4 v = *(const float4*)&hb[((size_t)xx << 9) + c0 + cc4];
      float4 bv = *(const float4*)&cb[c0 + cc4];
      sH[(cc4 + 0) * 33 + xx] = fmaxf(v.x * HSCALE + bv.x, 0.f);
      sH[(cc4 + 1) * 33 + xx] = fmaxf(v.y * HSCALE + bv.y, 0.f);
      sH[(cc4 + 2) * 33 + xx] = fmaxf(v.z * HSCALE + bv.z, 0.f);
      sH[(cc4 + 3) * 33 + xx] = fmaxf(v.w * HSCALE + bv.w, 0.f);
    }
    *(float4*)&sWt[tid << 2] = *(const float4*)&wslt[(c0 << 6) + (tid << 2)];
    __syncthreads();
#pragma unroll
    for (int cc = 0; cc < 16; ++cc) {
      float hv = sH[cc * 33 + x];
      const float4* wp = (const float4*)&sWt[(cc << 6) + (og << 3)];
      float4 w0 = wp[0], w1 = wp[1];
      acc[0] = fmaf(hv, w0.x, acc[0]); acc[1] = fmaf(hv, w0.y, acc[1]);
      acc[2] = fmaf(hv, w0.z, acc[2]); acc[3] = fmaf(hv, w0.w, acc[3]);
      acc[4] = fmaf(hv, w1.x, acc[4]); acc[5] = fmaf(hv, w1.y, acc[5]);
      acc[6] = fmaf(hv, w1.z, acc[6]); acc[7] = fmaf(hv, w1.w, acc[7]);
    }
  }
  __syncthreads();
#pragma unroll
  for (int j = 0; j < 8; ++j) {
    int o = (og << 3) + j;
    sOut[o * 33 + x] = acc[j] + wslb[o];
  }
  __syncthreads();

  const int p0 = (n << 12) + (y2 << 5);
  float* locs = out + O0 + (size_t)p0 * 36;
  for (int e = tid; e < 1152; e += 256) {
    int xp = e / 36, o = e - xp * 36;
    locs[e] = sOut[o * 33 + xp];
  }
  float* scrs = out + O1 + (size_t)p0 * 18;
  for (int e = tid; e < 576; e += 256) {
    int xp = e / 18, ss = e - xp * 18;
    scrs[e] = sOut[(36 + ss) * 33 + xp];
  }
  float* fg = fgbuf + (size_t)p0 * 9;   // [n][4096][9] flatten == p0*9
  for (int e = tid; e < 288; e += 256) {
    int xp = e / 9, a = e - xp * 9;
    float s0 = sOut[(36 + 2 * a) * 33 + xp];
    float s1 = sOut[(36 + 2 * a + 1) * 33 + xp];
    fg[e] = 1.0f / (1.0f + expf(s0 - s1));
  }
}

// ---------------------------------------------------------------------------
// 3. fused tail: decode | hist-scan | compact | sort8k | build_mask | reduce.
// grid 288 x 256, 64KB LDS -> co-resident; manual grid barriers.
// ---------------------------------------------------------------------------
__global__ __launch_bounds__(256) void tail_all(
    float* __restrict__ out, const float* __restrict__ fgbuf,
    float4* __restrict__ roibuf, u64* __restrict__ keys,
    float* __restrict__ anchor_out, u32* __restrict__ ghist,
    u32* __restrict__ partial, u32* __restrict__ cut, u32* __restrict__ cnt,
    u32* __restrict__ bar, u64* __restrict__ ckeys,
    float4* __restrict__ sbox, u64* __restrict__ alive,
    u64* __restrict__ maskbuf,
    const int* __restrict__ imgh_p, const int* __restrict__ imgw_p) {
  __shared__ __align__(16) char smraw[65536];
  u64* sk = (u64*)smraw;
  u32* ps = (u32*)smraw;
  u32* red = (u32*)(smraw + 1024);
  float4 (*jb)[64] = (float4(*)[64])smraw;
  float* ja = (float*)(smraw + 4096);

  const int b = blockIdx.x, tid = threadIdx.x;

  // ---------------- P0: decode + keys + histogram + out-init --------------
  {
    const int n = b / 144;
    const int k = (b - n * 144) * 256 + tid;
    int gid = b * 256 + tid;
    if (gid < 3600) {
      if (gid < 2400) out[O2 + gid] = 0.f;
      else if (gid < 3000) out[O3 + (gid - 2400)] = (float)((gid - 2400) / 300);
      else out[O5 + (gid - 3000)] = 0.f;
    }
    int a = k % 9;
    int p = k / 9;
    int py = p >> 6, px = p & 63;
    const double R[3] = {0.5, 1.0, 2.0};
    const double S[3] = {8.0, 16.0, 32.0};
    double r = R[a / 3], s = S[a - (a / 3) * 3];
    double hd = 16.0 * s * sqrt(r);
    double wd = 16.0 * s * sqrt(1.0 / r);
    float ay1 = (float)(8.0 - hd / 2.0) + (float)(py * 16);
    float ax1 = (float)(8.0 - wd / 2.0) + (float)(px * 16);
    float ay2 = (float)(8.0 + hd / 2.0) + (float)(py * 16);
    float ax2 = (float)(8.0 + wd / 2.0) + (float)(px * 16);
    if (n == 0) {
      float* ao = anchor_out + (size_t)k * 4;
      ao[0] = ay1; ao[1] = ax1; ao[2] = ay2; ao[3] = ax2;
    }
    float ahk = ay2 - ay1, awk = ax2 - ax1;
    float acy = ay1 + 0.5f * ahk, acx = ax1 + 0.5f * awk;
    const float* lp = out + O0 + ((size_t)(n * NANCH + k) << 2);
    float dy = lp[0], dx = lp[1], dh = lp[2], dw = lp[3];
    float cy = dy * ahk + acy;
    float cx = dx * awk + acx;
    float bh = expf(dh) * ahk;
    float bw = expf(dw) * awk;
    float img_h = (float)imgh_p[0], img_w = (float)imgw_p[0];
    float y1 = fminf(fmaxf(cy - 0.5f * bh, 0.f), img_h);
    float x1 = fminf(fmaxf(cx - 0.5f * bw, 0.f), img_w);
    float y2 = fminf(fmaxf(cy + 0.5f * bh, 0.f), img_h);
    float x2 = fminf(fmaxf(cx + 0.5f * bw, 0.f), img_w);
    bool valid = ((y2 - y1) >= 16.f) && ((x2 - x1) >= 16.f);
    float sc = valid ? fgbuf[n * NANCH + k] : -INFINITY;
    roibuf[n * NANCH + k] = make_float4(y1, x1, y2, x2);
    unsigned int bm = __float_as_uint(sc);
    unsigned int mm = bm ^ ((bm & 0x80000000u) ? 0xFFFFFFFFu : 0x80000000u);
    u32 hi = ~mm;
    keys[(n << 16) + k] = ((u64)hi << 32) | (unsigned int)k;
    atomicAdd(&ghist[(n << 18) + (hi >> 14)], 1u);
  }
  gridbar(bar, 288);

  // ---------------- P1: per-chunk partial sums (512 units) ----------------
  for (int u = b; u < 512; u += 288) {
    int n = u >> 8, chunk = u & 255;
    uint4 v = *(const uint4*)&ghist[(n << 18) + (chunk << 10) + (tid << 2)];
    u32 s = v.x + v.y + v.z + v.w;
#pragma unroll
    for (int off = 32; off > 0; off >>= 1) s += __shfl_down(s, off);
    if ((tid & 63) == 0) red[tid >> 6] = s;
    __syncthreads();
    if (tid == 0) partial[u] = red[0] + red[1] + red[2] + red[3];
    __syncthreads();
  }
  gridbar(bar, 576);

  // ---------------- P2: scan partials + find cut bin ----------------------
  if (b < 2) {
    const int n = b;
    u32 sown = partial[(n << 8) + tid];
    ps[tid] = sown;
    __syncthreads();
    for (int off = 1; off < 256; off <<= 1) {
      u32 v = (tid >= off) ? ps[tid - off] : 0;
      __syncthreads();
      ps[tid] += v;
      __syncthreads();
    }
    u32 cumEnd = ps[tid], cumStart = cumEnd - sown;
    if (cumStart < N_PRE && cumEnd >= N_PRE) {
      const u32* h = ghist + (n << 18) + (tid << 10);
      u32 c = cumStart;
      for (int i = 0; i < 1024; ++i) {
        c += h[i];
        if (c >= N_PRE) { cut[n] = (tid << 10) + i; break; }
      }
    }
  }
  gridbar(bar, 864);

  // ---------------- P3: compact bin <= cut into ckeys ---------------------
  {
    const int n = b / 144;
    const int k = (b - n * 144) * 256 + tid;
    u64 key = keys[(n << 16) + k];
    u32 bin = (u32)(key >> 46);
    if (bin <= cut[n]) {
      u32 pos = atomicAdd(&cnt[n], 1u);
      if (pos < 8192) ckeys[(n << 13) + pos] = key;
    }
  }
  gridbar(bar, 1152);

  // ---------------- P4: sort 8192 + gather sbox/alive (blocks 0,1) --------
  if (b < 2) {
    const int n = b;
    for (int i = tid; i < 8192; i += 256) sk[i] = ckeys[(n << 13) + i];
    __syncthreads();
    for (int k = 2; k <= 8192; k <<= 1) {
      for (int j = k >> 1; j > 0; j >>= 1) {
        for (int t = tid; t < 4096; t += 256) {
          int l = ((t & ~(j - 1)) << 1) | (t & (j - 1));
          int rr = l | j;
          bool asc = ((l & k) == 0);
          u64 a = sk[l], bb = sk[rr];
          if ((a > bb) == asc) { sk[l] = bb; sk[rr] = a; }
        }
        __syncthreads();
      }
    }
    for (int i = tid; i < NPADC; i += 256) {
      u64 kk = sk[i];
      bool valid = (i < N_PRE) && (((u32)(kk >> 32)) < 0xFF800000u);
      float4 bx = make_float4(0.f, 0.f, 0.f, 0.f);
      if (valid) bx = roibuf[(size_t)n * NANCH + (u32)(kk & 0xFFFFFFFFull)];
      sbox[n * NPADC + i] = bx;
      u64 bal = __ballot(valid);
      if ((tid & 63) == 0) alive[n * NW + (i >> 6)] = bal;
    }
  }
  gridbar(bar, 1440);

  // ---------------- P5: build FULL suppression matrix (768 units) ---------
  for (int u = b; u < 768; u += 288) {
    const int g = u % 96;
    const int rq = u / 96;
    const int q = rq & 3, n = rq >> 2;
    const int lane = tid & 63, wv = tid >> 6;
    const float4* sb = sbox + n * NPADC;
    float4 bi = sb[(g << 6) + lane];
    float ai = (bi.z - bi.x) * (bi.w - bi.y);
    u64* Mrow = maskbuf + ((size_t)(n * NPADC + (g << 6) + lane)) * NW;
#pragma unroll
    for (int it = 0; it < 6; ++it) {
      int w = q * 24 + (it << 2) + wv;
      float4 bjl = sb[(w << 6) + lane];
      jb[wv][lane] = bjl;
      ja[wv * 64 + lane] = (bjl.z - bjl.x) * (bjl.w - bjl.y);
      u64 bits = 0;
#pragma unroll 8
      for (int j = 0; j < 64; ++j) {
        float4 bj = jb[wv][j];
        float aj = ja[wv * 64 + j];
        float ih = fmaxf(fminf(bi.z, bj.z) - fmaxf(bi.x, bj.x), 0.f);
        float iw = fmaxf(fminf(bi.w, bj.w) - fmaxf(bi.y, bj.y), 0.f);
        float inter = ih * iw;
        bool bit = inter / (ai + aj - inter + 1e-9f) > 0.7f;
        bits |= ((u64)bit) << j;
      }
      Mrow[w] = bits;
    }
  }
  gridbar(bar, 1728);

  // ---------------- P6: greedy reduce (blocks 0,1; wave 0) ----------------
  if (b < 2 && tid < 64) {
    const int n = b, lane = tid;
    float* rois = out + O2 + n * (N_POST * 4);
    float* vmask = out + O5 + n * N_POST;
    const u64* A = alive + n * NW;
    const u64* Mb = maskbuf + (size_t)n * NPADC * NW;
    const float4* sb = sbox + n * NPADC;
    u64 aw0 = A[lane];
    u64 aw1 = (lane < 32) ? A[64 + lane] : 0ull;
    u64 accA = 0, accB = 0;
    int nk = 0;
    u64 dnext = Mb[(size_t)lane * NW + 0];
    float4 bnext = sb[lane];
    const u64 below = lane ? (~0ull >> (64 - lane)) : 0ull;

    for (int c = 0; c < 94; ++c) {
      u64 dcur = dnext;
      float4 bcur = bnext;
      if (c + 1 < 94) {
        dnext = Mb[(size_t)(((c + 1) << 6) + lane) * NW + (c + 1)];
        bnext = sb[((c + 1) << 6) + lane];
      }
      u64 wacc = (c < 64) ? bcast64(accA, c) : bcast64(accB, c - 64);
      u64 aw = (c < 64) ? bcast64(aw0, c) : bcast64(aw1, c - 64);
      u64 alive_u = aw & ~wacc;
      if (alive_u == 0ull) continue;

      u64 dmask = dcur & below;
      u64 rem = alive_u, kept = 0;
      while (rem) {
        int j = __builtin_ctzll(rem);
        kept |= 1ull << j;
        u64 col = __ballot((dmask >> j) & 1);
        rem &= ~(col | (1ull << j));
      }

      int npop = __popcll(kept);
      if ((kept >> lane) & 1ull) {
        int slot = nk + __popcll(kept & below);
        if (slot < N_POST) {
          rois[slot * 4 + 0] = bcur.x; rois[slot * 4 + 1] = bcur.y;
          rois[slot * 4 + 2] = bcur.z; rois[slot * 4 + 3] = bcur.w;
          vmask[slot] = 1.0f;
        }
      }
      if (nk + npop >= N_POST) break;
      nk += npop;

      u64 kk = kept;
      while (kk) {
        int j0 = __builtin_ctzll(kk); kk &= kk - 1;
        int j1 = kk ? __builtin_ctzll(kk) : j0; kk &= kk - 1;
        int j2 = kk ? __builtin_ctzll(kk) : j0; kk &= kk - 1;
        int j3 = kk ? __builtin_ctzll(kk) : j0; kk &= kk - 1;
        int j4 = kk ? __builtin_ctzll(kk) : j0; kk &= kk - 1;
        int j5 = kk ? __builtin_ctzll(kk) : j0; kk &= kk - 1;
        int j6 = kk ? __builtin_ctzll(kk) : j0; kk &= kk - 1;
        int j7 = kk ? __builtin_ctzll(kk) : j0; kk &= kk - 1;
        const u64* r0 = Mb + (size_t)((c << 6) + j0) * NW;
        const u64* r1 = Mb + (size_t)((c << 6) + j1) * NW;
        const u64* r2 = Mb + (size_t)((c << 6) + j2) * NW;
        const u64* r3 = Mb + (size_t)((c << 6) + j3) * NW;
        const u64* r4 = Mb + (size_t)((c << 6) + j4) * NW;
        const u64* r5 = Mb + (size_t)((c << 6) + j5) * NW;
        const u64* r6 = Mb + (size_t)((c << 6) + j6) * NW;
        const u64* r7 = Mb + (size_t)((c << 6) + j7) * NW;
        u64 oA = r0[lane] | r1[lane] | r2[lane] | r3[lane]
               | r4[lane] | r5[lane] | r6[lane] | r7[lane];
        u64 oB = 0;
        if (lane < 32)
          oB = r0[64 + lane] | r1[64 + lane] | r2[64 + lane] | r3[64 + lane]
             | r4[64 + lane] | r5[64 + lane] | r6[64 + lane] | r7[64 + lane];
        accA |= oA;
        accB |= oB;
      }
    }
  }
}

// ---------------------------------------------------------------------------
extern "C" void kernel_launch(void* const* d_in, const int* in_sizes, int n_in,
                              void* d_out, int out_size, void* d_ws, size_t ws_size,
                              hipStream_t stream) {
  const float* x        = (const float*)d_in[0];
  const float* conv1_w  = (const float*)d_in[1];
  const float* conv1_b  = (const float*)d_in[2];
  const float* score_w  = (const float*)d_in[3];
  const float* score_b  = (const float*)d_in[4];
  const float* loc_w    = (const float*)d_in[5];
  const float* loc_b    = (const float*)d_in[6];
  const int*   imgh_p   = (const int*)d_in[7];
  const int*   imgw_p   = (const int*)d_in[8];

  float* out = (float*)d_out;
  float* ws  = (float*)d_ws;

  _Float16* xhi = (_Float16*)(ws + WS_XHI);
  _Float16* xlo = (_Float16*)(ws + WS_XLO);
  _Float16* whi = (_Float16*)(ws + WS_WHI);
  _Float16* wlo = (_Float16*)(ws + WS_WLO);
  float* wslt   = ws + WS_WSLT;
  float* wslb   = ws + WS_WSLB;
  float* hbuf   = ws + WS_H;
  float* guard  = ws + WS_GUARD;
  float* fgbuf   = ws + WS_FG;
  float4* roibuf = (float4*)(ws + WS_ROI);
  u64* keys      = (u64*)(ws + WS_KEYS);
  float4* sbox   = (float4*)(ws + WS_SBOX);
  u64* alive     = (u64*)(ws + WS_ALIVE);
  u64* ckeys     = (u64*)(ws + WS_CKEYS);
  u32* cnt       = (u32*)(ws + WS_CNT);
  u32* bar       = ((u32*)(ws + WS_CNT)) + 2;
  u32* cut       = (u32*)(ws + WS_CUT);
  u32* part      = (u32*)(ws + WS_PART);
  u32* ghist     = (u32*)(ws + WS_HIST2);
  u64* maskbuf   = (u64*)(ws + WS_MASK);

  prep_all<<<5826, 256, 0, stream>>>(x, conv1_w, loc_w, score_w, loc_b, score_b,
                                     (float4*)hbuf, (float4*)guard,
                                     xhi, xlo, whi, wlo, wslt, wslb);

  conv_mfma<<<dim3(64, 4, 2), 256, 0, stream>>>(xhi, xlo, whi, wlo, guard, hbuf);

  head_kernel<<<dim3(128, 2), 256, 0, stream>>>(hbuf, conv1_b, wslt, wslb, out,
                                                fgbuf, (float4*)ckeys,
                                                (float4*)ghist, (float4*)cnt);

  tail_all<<<288, 256, 0, stream>>>(out, fgbuf, roibuf, keys, out + O4, ghist,
                                    part, cut, cnt, bar, ckeys, sbox, alive,
                                    maskbuf, imgh_p, imgw_p);
}